// Round 4
// baseline (1387.279 us; speedup 1.0000x reference)
//
#include <hip/hip_runtime.h>

#define NF 64      // hidden width (both layers)
#define NBLK 128   // chunks for the two-pass bucket sort
#define MAXNB 2048 // max buckets supported by LDS histograms (n <= 131072)

// =================== scan utilities ===================

__device__ inline int wave_incl_scan(int x, int lane) {
#pragma unroll
    for (int o = 1; o < 64; o <<= 1) { int y = __shfl_up(x, o, 64); if (lane >= o) x += y; }
    return x;
}

// 1024 elements per block (256 threads x 4); in-place safe
__global__ __launch_bounds__(256) void k_scan_a(const int* __restrict__ in, int* __restrict__ out,
                                                int* __restrict__ bsums, int n) {
    int t = threadIdx.x, lane = t & 63, wv = t >> 6;
    int base = blockIdx.x * 1024 + t * 4;
    int v[4]; int s = 0;
#pragma unroll
    for (int k = 0; k < 4; ++k) { int i = base + k; int x = (i < n) ? in[i] : 0; v[k] = s; s += x; }
    int incl = wave_incl_scan(s, lane);
    __shared__ int ws[4];
    if (lane == 63) ws[wv] = incl;
    __syncthreads();
    int wofs = 0;
#pragma unroll
    for (int w = 0; w < 4; ++w) if (w < wv) wofs += ws[w];
    int texcl = wofs + incl - s;
#pragma unroll
    for (int k = 0; k < 4; ++k) { int i = base + k; if (i < n) out[i] = texcl + v[k]; }
    if (t == 255) bsums[blockIdx.x] = wofs + incl;
}

// single-block exclusive scan over up to 2048 entries; in-place safe
__global__ __launch_bounds__(256) void k_scan_small(const int* __restrict__ cnt, int* __restrict__ ptr, int NB) {
    int t = threadIdx.x, lane = t & 63, wv = t >> 6;
    int base = t * 8;
    int local[8]; int s = 0;
#pragma unroll
    for (int k = 0; k < 8; ++k) { int i = base + k; int x = (i < NB) ? cnt[i] : 0; local[k] = s; s += x; }
    int incl = wave_incl_scan(s, lane);
    __shared__ int ws[4];
    if (lane == 63) ws[wv] = incl;
    __syncthreads();
    int wofs = 0;
#pragma unroll
    for (int w = 0; w < 4; ++w) if (w < wv) wofs += ws[w];
    int texcl = wofs + incl - s;
#pragma unroll
    for (int k = 0; k < 8; ++k) { int i = base + k; if (i < NB) ptr[i] = texcl + local[k]; }
}

__global__ __launch_bounds__(256) void k_scan_add(int* data, const int* __restrict__ bsums, int ntot) {
    int i = blockIdx.x * 256 + threadIdx.x;
    if (i < ntot) data[i] += bsums[i >> 10];
}

// =================== contention-free bucket sort (bucket = dst >> 6) ===================

// per-chunk LDS histogram -> hmat[bucket * NBLK + blk]
__global__ __launch_bounds__(256) void k_histA(const int* __restrict__ dst, int* __restrict__ hmat,
                                               int E, int NB, int chunk) {
    __shared__ int h[MAXNB];
    int blk = blockIdx.x;
    for (int i = threadIdx.x; i < NB; i += 256) h[i] = 0;
    __syncthreads();
    int beg = blk * chunk, end = beg + chunk; if (end > E) end = E;
    for (int e = beg + threadIdx.x; e < end; e += 256) atomicAdd(&h[dst[e] >> 6], 1);
    __syncthreads();
    for (int i = threadIdx.x; i < NB; i += 256) hmat[i * NBLK + blk] = h[i];
}

// place packed (src<<6)|(dst&63) using scanned hmat bases + LDS cursors (no global atomics)
__global__ __launch_bounds__(256) void k_placeB(const int* __restrict__ src, const int* __restrict__ dst,
                                                const int* __restrict__ hmat, int* __restrict__ pairs,
                                                int E, int NB, int chunk) {
    __shared__ int cur[MAXNB];
    int blk = blockIdx.x;
    for (int i = threadIdx.x; i < NB; i += 256) cur[i] = hmat[i * NBLK + blk];
    __syncthreads();
    int beg = blk * chunk, end = beg + chunk; if (end > E) end = E;
    for (int e = beg + threadIdx.x; e < end; e += 256) {
        int s = src[e], d = dst[e];
        int off = atomicAdd(&cur[d >> 6], 1);
        pairs[off] = (s << 6) | (d & 63);
    }
}

// bptr[b] = scanned hmat[b*NBLK]; bptr[NB] = E
__global__ __launch_bounds__(256) void k_bptr(const int* __restrict__ hmat, int* __restrict__ bptr,
                                              int NB, int E) {
    int b = blockIdx.x * 256 + threadIdx.x;
    if (b < NB) bptr[b] = hmat[b * NBLK];
    if (b == NB) bptr[NB] = E;
}

// per-bucket in-degree histogram -> dinv = rsqrt(1 + deg)
__global__ __launch_bounds__(256) void k_deg(const int* __restrict__ bptr, const int* __restrict__ pairs,
                                             float* __restrict__ dinv, int n) {
    __shared__ int h[64];
    int b = blockIdx.x;
    if (threadIdx.x < 64) h[threadIdx.x] = 0;
    __syncthreads();
    int beg = bptr[b], end = bptr[b + 1];
    for (int j = beg + threadIdx.x; j < end; j += 256) atomicAdd(&h[pairs[j] & 63], 1);
    __syncthreads();
    int node = (b << 6) + threadIdx.x;
    if (threadIdx.x < 64 && node < n) dinv[node] = rsqrtf(1.0f + (float)h[threadIdx.x]);
}

// =================== dense GEMM: hs[n][64] = (act(X + bin) @ W) * dinv[row] ===================
template<int K, bool IN_ACT, int ROWS>
__global__ __launch_bounds__(256) void k_gemm(
    const float* __restrict__ X, const float* __restrict__ W,
    const float* __restrict__ bin, const float* __restrict__ dinv,
    float* __restrict__ out, int n)
{
    __shared__ float Ws[K * NF];
    __shared__ float bs[K];
    __shared__ float xs[4][K];
    int t = threadIdx.x;
    for (int i = t; i < K * NF; i += 256) Ws[i] = W[i];
    if (IN_ACT) for (int i = t; i < K; i += 256) bs[i] = bin[i];
    __syncthreads();

    int wv = t >> 6, lane = t & 63;
    int row0 = blockIdx.x * ROWS + wv * (ROWS / 4);
    for (int r = 0; r < ROWS / 4; ++r) {
        int row = row0 + r;
        if (row >= n) return;
        for (int k = lane; k < K; k += 64) {
            float v = X[(size_t)row * K + k];
            if (IN_ACT) v = fmaxf(v + bs[k], 0.0f);
            xs[wv][k] = v;
        }
        float acc = 0.0f;
#pragma unroll
        for (int k = 0; k < K; ++k) acc = fmaf(xs[wv][k], Ws[k * NF + lane], acc);
        out[(size_t)row * NF + lane] = acc * dinv[row];
    }
}

// =================== fused aggregation: one block per bucket, LDS accumulator tile ===================
// out[d] = dinv[d] * ( hs[d] + sum_{s in N_in(d)} hs[s] ),  hs = h * dinv
__global__ __launch_bounds__(256) void k_agg(
    const float* __restrict__ hs, const float* __restrict__ dinv,
    const int* __restrict__ bptr, const int* __restrict__ pairs,
    float* __restrict__ out, int n)
{
    __shared__ float acc[64][NF];
    int b = blockIdx.x;
    int t = threadIdx.x, lane = t & 63, wv = t >> 6;
    int node0 = b << 6;

    // self-loop init
    for (int i = wv; i < 64; i += 4) {
        int node = node0 + i;
        acc[i][lane] = (node < n) ? hs[(size_t)node * NF + lane] : 0.0f;
    }
    __syncthreads();

    int beg = bptr[b], end = bptr[b + 1];
    // each wave processes 4 edges per iteration (4 gathers in flight)
    for (int j0 = beg + wv * 4; j0 < end; j0 += 16) {
        int m = end - j0; if (m > 4) m = 4;
        if (m == 4) {
            int p0 = pairs[j0], p1 = pairs[j0 + 1], p2 = pairs[j0 + 2], p3 = pairs[j0 + 3];
            float v0 = hs[(size_t)(p0 >> 6) * NF + lane];
            float v1 = hs[(size_t)(p1 >> 6) * NF + lane];
            float v2 = hs[(size_t)(p2 >> 6) * NF + lane];
            float v3 = hs[(size_t)(p3 >> 6) * NF + lane];
            atomicAdd(&acc[p0 & 63][lane], v0);
            atomicAdd(&acc[p1 & 63][lane], v1);
            atomicAdd(&acc[p2 & 63][lane], v2);
            atomicAdd(&acc[p3 & 63][lane], v3);
        } else {
            for (int k = 0; k < m; ++k) {
                int pk = pairs[j0 + k];
                atomicAdd(&acc[pk & 63][lane], hs[(size_t)(pk >> 6) * NF + lane]);
            }
        }
    }
    __syncthreads();

    for (int i = wv; i < 64; i += 4) {
        int node = node0 + i;
        if (node < n) out[(size_t)node * NF + lane] = acc[i][lane] * dinv[node];
    }
}

// =================== decoder ===================
__global__ __launch_bounds__(256) void k_decode(
    const float* __restrict__ A, const float* __restrict__ b2,
    const float* __restrict__ Wd, const float* __restrict__ bd,
    float* __restrict__ out, int n)
{
    int row = blockIdx.x * 4 + (threadIdx.x >> 6);
    if (row >= n) return;
    int lane = threadIdx.x & 63;
    float v = fmaxf(A[(size_t)row * NF + lane] + b2[lane], 0.0f) * Wd[lane];
#pragma unroll
    for (int o = 32; o > 0; o >>= 1) v += __shfl_xor(v, o, 64);
    if (lane == 0) out[row] = v + bd[0];
}

extern "C" void kernel_launch(void* const* d_in, const int* in_sizes, int n_in,
                              void* d_out, int out_size, void* d_ws, size_t ws_size,
                              hipStream_t stream) {
    const float* x  = (const float*)d_in[0];
    const int*   ei = (const int*)d_in[1];
    const float* W1 = (const float*)d_in[2];
    const float* b1 = (const float*)d_in[3];
    const float* W2 = (const float*)d_in[4];
    const float* b2 = (const float*)d_in[5];
    const float* Wd = (const float*)d_in[6];
    const float* bd = (const float*)d_in[7];
    float* out = (float*)d_out;

    int n = in_sizes[0] / 128;
    int E = in_sizes[1] / 2;
    const int* src = ei;
    const int* dst = ei + E;

    int NB = (n + 63) >> 6;                 // dst buckets of 64 nodes
    int chunk = (E + NBLK - 1) / NBLK;
    int ntot = NB * NBLK;                   // hist matrix size
    int nsb = (ntot + 1023) / 1024;         // scan blocks over hmat

    // workspace layout (4-byte elems)
    float* dinv  = (float*)d_ws;                    // n
    float* bufH  = dinv + n;                        // 64n
    float* bufA  = bufH + (size_t)n * NF;           // 64n
    int*   pairs = (int*)(bufA + (size_t)n * NF);   // E (persists across both layers)
    int*   hmat  = pairs + E;                       // NB*NBLK
    int*   bptr  = hmat + ntot;                     // NB+1
    int*   bsums = bptr + NB + 1;                   // nsb (<=1024)

    // ---- bucket sort by dst (contention-free) + dinv ----
    k_histA<<<NBLK, 256, 0, stream>>>(dst, hmat, E, NB, chunk);
    k_scan_a<<<nsb, 256, 0, stream>>>(hmat, hmat, bsums, ntot);
    k_scan_small<<<1, 256, 0, stream>>>(bsums, bsums, nsb);
    k_scan_add<<<(ntot + 255) / 256, 256, 0, stream>>>(hmat, bsums, ntot);
    k_bptr<<<(NB + 256) / 256, 256, 0, stream>>>(hmat, bptr, NB, E);
    k_placeB<<<NBLK, 256, 0, stream>>>(src, dst, hmat, pairs, E, NB, chunk);
    k_deg<<<NB, 256, 0, stream>>>(bptr, pairs, dinv, n);

    // ---- layer 1: hs = (x @ W1) * dinv ; agg ----
    k_gemm<128, false, 32><<<(n + 31) / 32, 256, 0, stream>>>(x, W1, nullptr, dinv, bufH, n);
    k_agg<<<NB, 256, 0, stream>>>(bufH, dinv, bptr, pairs, bufA, n);

    // ---- layer 2: hs = (relu(agg + b1) @ W2) * dinv ; agg ----
    k_gemm<64, true, 32><<<(n + 31) / 32, 256, 0, stream>>>(bufA, W2, b1, dinv, bufH, n);
    k_agg<<<NB, 256, 0, stream>>>(bufH, dinv, bptr, pairs, bufA, n);

    // ---- decoder ----
    k_decode<<<(n + 3) / 4, 256, 0, stream>>>(bufA, b2, Wd, bd, out, n);
}

// Round 5
// 326.684 us; speedup vs baseline: 4.2465x; 4.2465x over previous
//
#include <hip/hip_runtime.h>

#define NF 64      // hidden width (both layers)
#define NBLK 128   // chunks for the two-pass bucket sort
#define MAXNB 2048 // max buckets supported by LDS histograms (n <= 131072)

// =================== scan utilities ===================

__device__ inline int wave_incl_scan(int x, int lane) {
#pragma unroll
    for (int o = 1; o < 64; o <<= 1) { int y = __shfl_up(x, o, 64); if (lane >= o) x += y; }
    return x;
}

// 1024 elements per block (256 threads x 4); in-place safe (reads precede barrier, writes follow)
__global__ __launch_bounds__(256) void k_scan_a(const int* __restrict__ in, int* __restrict__ out,
                                                int* __restrict__ bsums, int n) {
    int t = threadIdx.x, lane = t & 63, wv = t >> 6;
    int base = blockIdx.x * 1024 + t * 4;
    int v[4]; int s = 0;
#pragma unroll
    for (int k = 0; k < 4; ++k) { int i = base + k; int x = (i < n) ? in[i] : 0; v[k] = s; s += x; }
    int incl = wave_incl_scan(s, lane);
    __shared__ int ws[4];
    if (lane == 63) ws[wv] = incl;
    __syncthreads();
    int wofs = 0;
#pragma unroll
    for (int w = 0; w < 4; ++w) if (w < wv) wofs += ws[w];
    int texcl = wofs + incl - s;
#pragma unroll
    for (int k = 0; k < 4; ++k) { int i = base + k; if (i < n) out[i] = texcl + v[k]; }
    if (t == 255) bsums[blockIdx.x] = wofs + incl;
}

// single-block exclusive scan over up to 2048 entries; in-place safe
__global__ __launch_bounds__(256) void k_scan_small(const int* __restrict__ cnt, int* __restrict__ ptr, int NB) {
    int t = threadIdx.x, lane = t & 63, wv = t >> 6;
    int base = t * 8;
    int local[8]; int s = 0;
#pragma unroll
    for (int k = 0; k < 8; ++k) { int i = base + k; int x = (i < NB) ? cnt[i] : 0; local[k] = s; s += x; }
    int incl = wave_incl_scan(s, lane);
    __shared__ int ws[4];
    if (lane == 63) ws[wv] = incl;
    __syncthreads();
    int wofs = 0;
#pragma unroll
    for (int w = 0; w < 4; ++w) if (w < wv) wofs += ws[w];
    int texcl = wofs + incl - s;
#pragma unroll
    for (int k = 0; k < 8; ++k) { int i = base + k; if (i < NB) ptr[i] = texcl + local[k]; }
}

__global__ __launch_bounds__(256) void k_scan_add(int* data, const int* __restrict__ bsums, int ntot) {
    int i = blockIdx.x * 256 + threadIdx.x;
    if (i < ntot) data[i] += bsums[i >> 10];
}

// =================== contention-free bucket sort (bucket = dst >> 6) ===================

// per-chunk LDS histogram -> hmat[bucket * NBLK + blk]
__global__ __launch_bounds__(256) void k_histA(const int* __restrict__ dst, int* __restrict__ hmat,
                                               int E, int NB, int chunk) {
    __shared__ int h[MAXNB];
    int blk = blockIdx.x;
    for (int i = threadIdx.x; i < NB; i += 256) h[i] = 0;
    __syncthreads();
    int beg = blk * chunk, end = beg + chunk; if (end > E) end = E;
    for (int e = beg + threadIdx.x; e < end; e += 256) atomicAdd(&h[dst[e] >> 6], 1);
    __syncthreads();
    for (int i = threadIdx.x; i < NB; i += 256) hmat[i * NBLK + blk] = h[i];
}

// place packed (src<<6)|(dst&63) using scanned hmat bases + LDS cursors (no global atomics)
__global__ __launch_bounds__(256) void k_placeB(const int* __restrict__ src, const int* __restrict__ dst,
                                                const int* __restrict__ hmat, int* __restrict__ pairs,
                                                int E, int NB, int chunk) {
    __shared__ int cur[MAXNB];
    int blk = blockIdx.x;
    for (int i = threadIdx.x; i < NB; i += 256) cur[i] = hmat[i * NBLK + blk];
    __syncthreads();
    int beg = blk * chunk, end = beg + chunk; if (end > E) end = E;
    for (int e = beg + threadIdx.x; e < end; e += 256) {
        int s = src[e], d = dst[e];
        int off = atomicAdd(&cur[d >> 6], 1);
        pairs[off] = (s << 6) | (d & 63);
    }
}

// bptr[b] = scanned hmat[b*NBLK]; bptr[NB] = E
__global__ __launch_bounds__(256) void k_bptr(const int* __restrict__ hmat, int* __restrict__ bptr,
                                              int NB, int E) {
    int b = blockIdx.x * 256 + threadIdx.x;
    if (b < NB) bptr[b] = hmat[b * NBLK];
    if (b == NB) bptr[NB] = E;
}

// per-bucket node histogram via LDS atomics -> dense counts write (no global atomics)
__global__ __launch_bounds__(256) void k_lhist(const int* __restrict__ bptr, const int* __restrict__ pairs,
                                               int* __restrict__ counts, int n) {
    __shared__ int h[64];
    int b = blockIdx.x;
    if (threadIdx.x < 64) h[threadIdx.x] = 0;
    __syncthreads();
    int beg = bptr[b], end = bptr[b + 1];
    for (int j = beg + threadIdx.x; j < end; j += 256) atomicAdd(&h[pairs[j] & 63], 1);
    __syncthreads();
    int node = (b << 6) + threadIdx.x;
    if (threadIdx.x < 64 && node < n) counts[node] = h[threadIdx.x];
}

// finalize row_ptr; dinv = rsqrt(1 + in-degree)
__global__ __launch_bounds__(256) void k_scan_c(int* __restrict__ rp, const int* __restrict__ bsums,
                                                const int* __restrict__ cnt, float* __restrict__ dinv, int n) {
    int i = blockIdx.x * 256 + threadIdx.x;
    if (i < n) {
        rp[i] += bsums[i >> 10];
        dinv[i] = rsqrtf(1.0f + (float)cnt[i]);
    }
}

// per-bucket CSR placement via LDS cursors; col writes dense within bucket region
__global__ __launch_bounds__(256) void k_place(const int* __restrict__ bptr, const int* __restrict__ pairs,
                                               const int* __restrict__ row_ptr, int* __restrict__ col, int n) {
    __shared__ int cur[64];
    int b = blockIdx.x;
    int node = (b << 6) + threadIdx.x;
    if (threadIdx.x < 64) cur[threadIdx.x] = (node < n) ? row_ptr[node] : 0;
    __syncthreads();
    int beg = bptr[b], end = bptr[b + 1];
    for (int j = beg + threadIdx.x; j < end; j += 256) {
        int pk = pairs[j];
        int p = atomicAdd(&cur[pk & 63], 1);
        col[p] = pk >> 6;
    }
}

// =================== dense GEMM: hs[n][64] = (act(X + bin) @ W) * dinv[row] ===================
template<int K, bool IN_ACT, int ROWS>
__global__ __launch_bounds__(256) void k_gemm(
    const float* __restrict__ X, const float* __restrict__ W,
    const float* __restrict__ bin, const float* __restrict__ dinv,
    float* __restrict__ out, int n)
{
    __shared__ float Ws[K * NF];
    __shared__ float bs[K];
    __shared__ float xs[4][K];
    int t = threadIdx.x;
    for (int i = t; i < K * NF; i += 256) Ws[i] = W[i];
    if (IN_ACT) for (int i = t; i < K; i += 256) bs[i] = bin[i];
    __syncthreads();

    int wv = t >> 6, lane = t & 63;
    int row0 = blockIdx.x * ROWS + wv * (ROWS / 4);
    for (int r = 0; r < ROWS / 4; ++r) {
        int row = row0 + r;
        if (row >= n) return;
        for (int k = lane; k < K; k += 64) {
            float v = X[(size_t)row * K + k];
            if (IN_ACT) v = fmaxf(v + bs[k], 0.0f);
            xs[wv][k] = v;
        }
        float acc = 0.0f;
#pragma unroll
        for (int k = 0; k < K; ++k) acc = fmaf(xs[wv][k], Ws[k * NF + lane], acc);
        out[(size_t)row * NF + lane] = acc * dinv[row];
    }
}

// =================== pull aggregation (float4, 4 sources per wave-load, 8-deep) ===================
// out[d] = dinv[d] * ( hs[d] + sum_{s in N_in(d)} hs[s] ),  hs = h * dinv
// 16-lane group g loads source row (edge k+u*4+g) as float4/lane; 8 loads (32 edges) in flight.
__global__ __launch_bounds__(256) void k_pull(
    const float* __restrict__ hs, const float* __restrict__ dinv,
    const int* __restrict__ row_ptr, const int* __restrict__ cnt,
    const int* __restrict__ col, float* __restrict__ out, int n)
{
    int d = blockIdx.x * 4 + (threadIdx.x >> 6);
    if (d >= n) return;
    int lane = threadIdx.x & 63;
    int grp = lane >> 4;
    int fo = (lane & 15) << 2;               // feature offset (floats)
    int beg = row_ptr[d], deg = cnt[d];

    float4 acc = make_float4(0.0f, 0.0f, 0.0f, 0.0f);
    if (grp == 0) acc = *(const float4*)(hs + (size_t)d * NF + fo);  // self-loop (grp0 only)

    for (int j0 = 0; j0 < deg; j0 += 64) {
        int m = deg - j0; if (m > 64) m = 64;
        int idx = (lane < m) ? col[beg + j0 + lane] : 0;
        for (int k = 0; k < m; k += 32) {
#pragma unroll
            for (int u = 0; u < 8; ++u) {
                int kk = k + u * 4 + grp;
                int s = __shfl(idx, (kk < m) ? kk : (m - 1), 64);  // clamp: dup loads hit L1
                const float4 v = *(const float4*)(hs + (size_t)s * NF + fo);
                if (kk < m) { acc.x += v.x; acc.y += v.y; acc.z += v.z; acc.w += v.w; }
            }
        }
    }
    // reduce the 4 lane-groups (xor 32 then 16 keeps lane&15 invariant)
    acc.x += __shfl_xor(acc.x, 32, 64); acc.y += __shfl_xor(acc.y, 32, 64);
    acc.z += __shfl_xor(acc.z, 32, 64); acc.w += __shfl_xor(acc.w, 32, 64);
    acc.x += __shfl_xor(acc.x, 16, 64); acc.y += __shfl_xor(acc.y, 16, 64);
    acc.z += __shfl_xor(acc.z, 16, 64); acc.w += __shfl_xor(acc.w, 16, 64);

    if (grp == 0) {
        float di = dinv[d];
        float4 r = make_float4(acc.x * di, acc.y * di, acc.z * di, acc.w * di);
        *(float4*)(out + (size_t)d * NF + fo) = r;
    }
}

// =================== decoder ===================
__global__ __launch_bounds__(256) void k_decode(
    const float* __restrict__ A, const float* __restrict__ b2,
    const float* __restrict__ Wd, const float* __restrict__ bd,
    float* __restrict__ out, int n)
{
    int row = blockIdx.x * 4 + (threadIdx.x >> 6);
    if (row >= n) return;
    int lane = threadIdx.x & 63;
    float v = fmaxf(A[(size_t)row * NF + lane] + b2[lane], 0.0f) * Wd[lane];
#pragma unroll
    for (int o = 32; o > 0; o >>= 1) v += __shfl_xor(v, o, 64);
    if (lane == 0) out[row] = v + bd[0];
}

extern "C" void kernel_launch(void* const* d_in, const int* in_sizes, int n_in,
                              void* d_out, int out_size, void* d_ws, size_t ws_size,
                              hipStream_t stream) {
    const float* x  = (const float*)d_in[0];
    const int*   ei = (const int*)d_in[1];
    const float* W1 = (const float*)d_in[2];
    const float* b1 = (const float*)d_in[3];
    const float* W2 = (const float*)d_in[4];
    const float* b2 = (const float*)d_in[5];
    const float* Wd = (const float*)d_in[6];
    const float* bd = (const float*)d_in[7];
    float* out = (float*)d_out;

    int n = in_sizes[0] / 128;
    int E = in_sizes[1] / 2;
    const int* src = ei;
    const int* dst = ei + E;

    int NB = (n + 63) >> 6;                 // dst buckets of 64 nodes
    int chunk = (E + NBLK - 1) / NBLK;
    int ntot = NB * NBLK;                   // hist matrix size
    int nsb = (ntot + 1023) / 1024;         // scan blocks over hmat
    int nb  = (n + 1023) / 1024;            // scan blocks over node counts

    // workspace layout (4-byte elems) — pairs aliases bufH (build finishes before gemm1)
    float* dinv    = (float*)d_ws;                    // n
    float* bufH    = dinv + n;                        // 64n
    float* bufA    = bufH + (size_t)n * NF;           // 64n
    int*   counts  = (int*)(bufA + (size_t)n * NF);   // n
    int*   row_ptr = counts + n;                      // n
    int*   col     = row_ptr + n;                     // E
    int*   hmat    = col + E;                         // NB*NBLK
    int*   bptr    = hmat + ntot;                     // NB+1
    int*   bsums   = bptr + NB + 1;                   // <=1024
    int*   pairs   = (int*)bufH;                      // E (build lifetime only)

    // ---- bucket sort by dst (contention-free) ----
    k_histA<<<NBLK, 256, 0, stream>>>(dst, hmat, E, NB, chunk);
    k_scan_a<<<nsb, 256, 0, stream>>>(hmat, hmat, bsums, ntot);
    k_scan_small<<<1, 256, 0, stream>>>(bsums, bsums, nsb);
    k_scan_add<<<(ntot + 255) / 256, 256, 0, stream>>>(hmat, bsums, ntot);
    k_bptr<<<(NB + 256) / 256, 256, 0, stream>>>(hmat, bptr, NB, E);
    k_placeB<<<NBLK, 256, 0, stream>>>(src, dst, hmat, pairs, E, NB, chunk);

    // ---- node-level CSR + dinv ----
    k_lhist<<<NB, 256, 0, stream>>>(bptr, pairs, counts, n);
    k_scan_a<<<nb, 256, 0, stream>>>(counts, row_ptr, bsums, n);
    k_scan_small<<<1, 256, 0, stream>>>(bsums, bsums, nb);
    k_scan_c<<<(n + 255) / 256, 256, 0, stream>>>(row_ptr, bsums, counts, dinv, n);
    k_place<<<NB, 256, 0, stream>>>(bptr, pairs, row_ptr, col, n);

    // ---- layer 1: hs = (x @ W1) * dinv ; agg = pull ----  (pairs dead from here)
    k_gemm<128, false, 32><<<(n + 31) / 32, 256, 0, stream>>>(x, W1, nullptr, dinv, bufH, n);
    k_pull<<<(n + 3) / 4, 256, 0, stream>>>(bufH, dinv, row_ptr, counts, col, bufA, n);

    // ---- layer 2: hs = (relu(agg + b1) @ W2) * dinv ; agg = pull ----
    k_gemm<64, true, 32><<<(n + 31) / 32, 256, 0, stream>>>(bufA, W2, b1, dinv, bufH, n);
    k_pull<<<(n + 3) / 4, 256, 0, stream>>>(bufH, dinv, row_ptr, counts, col, bufA, n);

    // ---- decoder ----
    k_decode<<<(n + 3) / 4, 256, 0, stream>>>(bufA, b2, Wd, bd, out, n);
}

// Round 6
// 268.492 us; speedup vs baseline: 5.1669x; 1.2167x over previous
//
#include <hip/hip_runtime.h>

#define NF 64      // hidden width (both layers)
#define NBLK 128   // chunks for the two-pass bucket sort
#define MAXNB 2048 // max buckets supported by LDS histograms (n <= 131072)

// =================== scan utilities ===================

__device__ inline int wave_incl_scan(int x, int lane) {
#pragma unroll
    for (int o = 1; o < 64; o <<= 1) { int y = __shfl_up(x, o, 64); if (lane >= o) x += y; }
    return x;
}

// 1024 elements per block (256 threads x 4); in-place safe
__global__ __launch_bounds__(256) void k_scan_a(const int* __restrict__ in, int* __restrict__ out,
                                                int* __restrict__ bsums, int n) {
    int t = threadIdx.x, lane = t & 63, wv = t >> 6;
    int base = blockIdx.x * 1024 + t * 4;
    int v[4]; int s = 0;
#pragma unroll
    for (int k = 0; k < 4; ++k) { int i = base + k; int x = (i < n) ? in[i] : 0; v[k] = s; s += x; }
    int incl = wave_incl_scan(s, lane);
    __shared__ int ws[4];
    if (lane == 63) ws[wv] = incl;
    __syncthreads();
    int wofs = 0;
#pragma unroll
    for (int w = 0; w < 4; ++w) if (w < wv) wofs += ws[w];
    int texcl = wofs + incl - s;
#pragma unroll
    for (int k = 0; k < 4; ++k) { int i = base + k; if (i < n) out[i] = texcl + v[k]; }
    if (t == 255) bsums[blockIdx.x] = wofs + incl;
}

// single-block exclusive scan over up to 2048 entries; in-place safe
__global__ __launch_bounds__(256) void k_scan_small(const int* __restrict__ cnt, int* __restrict__ ptr, int NB) {
    int t = threadIdx.x, lane = t & 63, wv = t >> 6;
    int base = t * 8;
    int local[8]; int s = 0;
#pragma unroll
    for (int k = 0; k < 8; ++k) { int i = base + k; int x = (i < NB) ? cnt[i] : 0; local[k] = s; s += x; }
    int incl = wave_incl_scan(s, lane);
    __shared__ int ws[4];
    if (lane == 63) ws[wv] = incl;
    __syncthreads();
    int wofs = 0;
#pragma unroll
    for (int w = 0; w < 4; ++w) if (w < wv) wofs += ws[w];
    int texcl = wofs + incl - s;
#pragma unroll
    for (int k = 0; k < 8; ++k) { int i = base + k; if (i < NB) ptr[i] = texcl + local[k]; }
}

__global__ __launch_bounds__(256) void k_scan_add(int* data, const int* __restrict__ bsums, int ntot) {
    int i = blockIdx.x * 256 + threadIdx.x;
    if (i < ntot) data[i] += bsums[i >> 10];
}

// =================== contention-free bucket sort (bucket = dst >> 6) ===================

__global__ __launch_bounds__(256) void k_histA(const int* __restrict__ dst, int* __restrict__ hmat,
                                               int E, int NB, int chunk) {
    __shared__ int h[MAXNB];
    int blk = blockIdx.x;
    for (int i = threadIdx.x; i < NB; i += 256) h[i] = 0;
    __syncthreads();
    int beg = blk * chunk, end = beg + chunk; if (end > E) end = E;
    for (int e = beg + threadIdx.x; e < end; e += 256) atomicAdd(&h[dst[e] >> 6], 1);
    __syncthreads();
    for (int i = threadIdx.x; i < NB; i += 256) hmat[i * NBLK + blk] = h[i];
}

__global__ __launch_bounds__(256) void k_placeB(const int* __restrict__ src, const int* __restrict__ dst,
                                                const int* __restrict__ hmat, int* __restrict__ pairs,
                                                int E, int NB, int chunk) {
    __shared__ int cur[MAXNB];
    int blk = blockIdx.x;
    for (int i = threadIdx.x; i < NB; i += 256) cur[i] = hmat[i * NBLK + blk];
    __syncthreads();
    int beg = blk * chunk, end = beg + chunk; if (end > E) end = E;
    for (int e = beg + threadIdx.x; e < end; e += 256) {
        int s = src[e], d = dst[e];
        int off = atomicAdd(&cur[d >> 6], 1);
        pairs[off] = (s << 6) | (d & 63);
    }
}

__global__ __launch_bounds__(256) void k_bptr(const int* __restrict__ hmat, int* __restrict__ bptr,
                                              int NB, int E) {
    int b = blockIdx.x * 256 + threadIdx.x;
    if (b < NB) bptr[b] = hmat[b * NBLK];
    if (b == NB) bptr[NB] = E;
}

__global__ __launch_bounds__(256) void k_lhist(const int* __restrict__ bptr, const int* __restrict__ pairs,
                                               int* __restrict__ counts, int n) {
    __shared__ int h[64];
    int b = blockIdx.x;
    if (threadIdx.x < 64) h[threadIdx.x] = 0;
    __syncthreads();
    int beg = bptr[b], end = bptr[b + 1];
    for (int j = beg + threadIdx.x; j < end; j += 256) atomicAdd(&h[pairs[j] & 63], 1);
    __syncthreads();
    int node = (b << 6) + threadIdx.x;
    if (threadIdx.x < 64 && node < n) counts[node] = h[threadIdx.x];
}

__global__ __launch_bounds__(256) void k_scan_c(int* __restrict__ rp, const int* __restrict__ bsums,
                                                const int* __restrict__ cnt, float* __restrict__ dinv, int n) {
    int i = blockIdx.x * 256 + threadIdx.x;
    if (i < n) {
        rp[i] += bsums[i >> 10];
        dinv[i] = rsqrtf(1.0f + (float)cnt[i]);
    }
}

__global__ __launch_bounds__(256) void k_place(const int* __restrict__ bptr, const int* __restrict__ pairs,
                                               const int* __restrict__ row_ptr, int* __restrict__ col, int n) {
    __shared__ int cur[64];
    int b = blockIdx.x;
    int node = (b << 6) + threadIdx.x;
    if (threadIdx.x < 64) cur[threadIdx.x] = (node < n) ? row_ptr[node] : 0;
    __syncthreads();
    int beg = bptr[b], end = bptr[b + 1];
    for (int j = beg + threadIdx.x; j < end; j += 256) {
        int pk = pairs[j];
        int p = atomicAdd(&cur[pk & 63], 1);
        col[p] = pk >> 6;
    }
}

// =================== register-blocked GEMM ===================
// hs[n][64] = (X @ W) * dinv[row].  Block: 128 rows x 64 cols. Thread: 8 rows x 4 cols.
// W in LDS (broadcast b128 reads); x straight from global as float4 (rows are block-exclusive).
template<int K>
__global__ __launch_bounds__(256, 2) void k_gemm(
    const float* __restrict__ X, const float* __restrict__ W,
    const float* __restrict__ dinv, float* __restrict__ out, int n)
{
    __shared__ float Ws[K * NF];
    int t = threadIdx.x;
    for (int i = t; i < K * NF / 4; i += 256) ((float4*)Ws)[i] = ((const float4*)W)[i];
    __syncthreads();

    int c0 = (t & 15) * 4;                    // 16 col-groups x 4 cols
    int row0 = blockIdx.x * 128 + (t >> 4) * 8;  // 16 row-groups x 8 rows

    const float* Xr[8];
#pragma unroll
    for (int r = 0; r < 8; ++r) {
        int row = row0 + r; if (row >= n) row = n - 1;   // clamp: dup loads, stores guarded
        Xr[r] = X + (size_t)row * K;
    }

    float4 acc[8];
#pragma unroll
    for (int r = 0; r < 8; ++r) acc[r] = make_float4(0.f, 0.f, 0.f, 0.f);

#pragma unroll 2
    for (int k0 = 0; k0 < K; k0 += 4) {
        float4 xv[8];
#pragma unroll
        for (int r = 0; r < 8; ++r) xv[r] = *(const float4*)(Xr[r] + k0);
        float4 w0 = *(const float4*)(&Ws[(k0 + 0) * NF + c0]);
        float4 w1 = *(const float4*)(&Ws[(k0 + 1) * NF + c0]);
        float4 w2 = *(const float4*)(&Ws[(k0 + 2) * NF + c0]);
        float4 w3 = *(const float4*)(&Ws[(k0 + 3) * NF + c0]);
#pragma unroll
        for (int r = 0; r < 8; ++r) {
            acc[r].x = fmaf(xv[r].x, w0.x, acc[r].x); acc[r].y = fmaf(xv[r].x, w0.y, acc[r].y);
            acc[r].z = fmaf(xv[r].x, w0.z, acc[r].z); acc[r].w = fmaf(xv[r].x, w0.w, acc[r].w);
            acc[r].x = fmaf(xv[r].y, w1.x, acc[r].x); acc[r].y = fmaf(xv[r].y, w1.y, acc[r].y);
            acc[r].z = fmaf(xv[r].y, w1.z, acc[r].z); acc[r].w = fmaf(xv[r].y, w1.w, acc[r].w);
            acc[r].x = fmaf(xv[r].z, w2.x, acc[r].x); acc[r].y = fmaf(xv[r].z, w2.y, acc[r].y);
            acc[r].z = fmaf(xv[r].z, w2.z, acc[r].z); acc[r].w = fmaf(xv[r].z, w2.w, acc[r].w);
            acc[r].x = fmaf(xv[r].w, w3.x, acc[r].x); acc[r].y = fmaf(xv[r].w, w3.y, acc[r].y);
            acc[r].z = fmaf(xv[r].w, w3.z, acc[r].z); acc[r].w = fmaf(xv[r].w, w3.w, acc[r].w);
        }
    }

#pragma unroll
    for (int r = 0; r < 8; ++r) {
        int row = row0 + r;
        if (row < n) {
            float di = dinv[row];
            float4 o = make_float4(acc[r].x * di, acc[r].y * di, acc[r].z * di, acc[r].w * di);
            *(float4*)(out + (size_t)row * NF + c0) = o;
        }
    }
}

// =================== pull aggregation (float4, 4 sources per wave-load, 8-deep) ===================
// out[d] = relu( dinv[d] * ( hs[d] + sum_{s in N_in(d)} hs[s] ) + bias ),  hs = h * dinv
__global__ __launch_bounds__(256) void k_pull(
    const float* __restrict__ hs, const float* __restrict__ dinv,
    const int* __restrict__ row_ptr, const int* __restrict__ cnt,
    const int* __restrict__ col, const float* __restrict__ bias,
    float* __restrict__ out, int n)
{
    int d = blockIdx.x * 4 + (threadIdx.x >> 6);
    if (d >= n) return;
    int lane = threadIdx.x & 63;
    int grp = lane >> 4;
    int fo = (lane & 15) << 2;               // feature offset (floats)
    int beg = row_ptr[d], deg = cnt[d];

    float4 acc = make_float4(0.0f, 0.0f, 0.0f, 0.0f);
    if (grp == 0) acc = *(const float4*)(hs + (size_t)d * NF + fo);  // self-loop (grp0 only)

    for (int j0 = 0; j0 < deg; j0 += 64) {
        int m = deg - j0; if (m > 64) m = 64;
        int idx = (lane < m) ? col[beg + j0 + lane] : 0;
        for (int k = 0; k < m; k += 32) {
#pragma unroll
            for (int u = 0; u < 8; ++u) {
                int kk = k + u * 4 + grp;
                int s = __shfl(idx, (kk < m) ? kk : (m - 1), 64);  // clamp: dup loads hit L1
                const float4 v = *(const float4*)(hs + (size_t)s * NF + fo);
                if (kk < m) { acc.x += v.x; acc.y += v.y; acc.z += v.z; acc.w += v.w; }
            }
        }
    }
    acc.x += __shfl_xor(acc.x, 32, 64); acc.y += __shfl_xor(acc.y, 32, 64);
    acc.z += __shfl_xor(acc.z, 32, 64); acc.w += __shfl_xor(acc.w, 32, 64);
    acc.x += __shfl_xor(acc.x, 16, 64); acc.y += __shfl_xor(acc.y, 16, 64);
    acc.z += __shfl_xor(acc.z, 16, 64); acc.w += __shfl_xor(acc.w, 16, 64);

    if (grp == 0) {
        float di = dinv[d];
        float4 bv = *(const float4*)(bias + fo);
        float4 r;
        r.x = fmaxf(fmaf(acc.x, di, bv.x), 0.0f);
        r.y = fmaxf(fmaf(acc.y, di, bv.y), 0.0f);
        r.z = fmaxf(fmaf(acc.z, di, bv.z), 0.0f);
        r.w = fmaxf(fmaf(acc.w, di, bv.w), 0.0f);
        *(float4*)(out + (size_t)d * NF + fo) = r;
    }
}

// =================== decoder: out[i] = A[i] . Wd + bd  (A already relu'd+biased) ===================
__global__ __launch_bounds__(256) void k_decode(
    const float* __restrict__ A, const float* __restrict__ Wd,
    const float* __restrict__ bd, float* __restrict__ out, int n)
{
    int row = blockIdx.x * 4 + (threadIdx.x >> 6);
    if (row >= n) return;
    int lane = threadIdx.x & 63;
    float v = A[(size_t)row * NF + lane] * Wd[lane];
#pragma unroll
    for (int o = 32; o > 0; o >>= 1) v += __shfl_xor(v, o, 64);
    if (lane == 0) out[row] = v + bd[0];
}

extern "C" void kernel_launch(void* const* d_in, const int* in_sizes, int n_in,
                              void* d_out, int out_size, void* d_ws, size_t ws_size,
                              hipStream_t stream) {
    const float* x  = (const float*)d_in[0];
    const int*   ei = (const int*)d_in[1];
    const float* W1 = (const float*)d_in[2];
    const float* b1 = (const float*)d_in[3];
    const float* W2 = (const float*)d_in[4];
    const float* b2 = (const float*)d_in[5];
    const float* Wd = (const float*)d_in[6];
    const float* bd = (const float*)d_in[7];
    float* out = (float*)d_out;

    int n = in_sizes[0] / 128;
    int E = in_sizes[1] / 2;
    const int* src = ei;
    const int* dst = ei + E;

    int NB = (n + 63) >> 6;                 // dst buckets of 64 nodes
    int chunk = (E + NBLK - 1) / NBLK;
    int ntot = NB * NBLK;                   // hist matrix size
    int nsb = (ntot + 1023) / 1024;         // scan blocks over hmat
    int nb  = (n + 1023) / 1024;            // scan blocks over node counts

    // workspace layout (4-byte elems) — pairs aliases bufH (build finishes before gemm1)
    float* dinv    = (float*)d_ws;                    // n
    float* bufH    = dinv + n;                        // 64n
    float* bufA    = bufH + (size_t)n * NF;           // 64n
    int*   counts  = (int*)(bufA + (size_t)n * NF);   // n
    int*   row_ptr = counts + n;                      // n
    int*   col     = row_ptr + n;                     // E
    int*   hmat    = col + E;                         // NB*NBLK
    int*   bptr    = hmat + ntot;                     // NB+1
    int*   bsums   = bptr + NB + 1;                   // <=1024
    int*   pairs   = (int*)bufH;                      // E (build lifetime only)

    // ---- bucket sort by dst (contention-free) ----
    k_histA<<<NBLK, 256, 0, stream>>>(dst, hmat, E, NB, chunk);
    k_scan_a<<<nsb, 256, 0, stream>>>(hmat, hmat, bsums, ntot);
    k_scan_small<<<1, 256, 0, stream>>>(bsums, bsums, nsb);
    k_scan_add<<<(ntot + 255) / 256, 256, 0, stream>>>(hmat, bsums, ntot);
    k_bptr<<<(NB + 256) / 256, 256, 0, stream>>>(hmat, bptr, NB, E);
    k_placeB<<<NBLK, 256, 0, stream>>>(src, dst, hmat, pairs, E, NB, chunk);

    // ---- node-level CSR + dinv ----
    k_lhist<<<NB, 256, 0, stream>>>(bptr, pairs, counts, n);
    k_scan_a<<<nb, 256, 0, stream>>>(counts, row_ptr, bsums, n);
    k_scan_small<<<1, 256, 0, stream>>>(bsums, bsums, nb);
    k_scan_c<<<(n + 255) / 256, 256, 0, stream>>>(row_ptr, bsums, counts, dinv, n);
    k_place<<<NB, 256, 0, stream>>>(bptr, pairs, row_ptr, col, n);

    // ---- layer 1: hs = (x @ W1) * dinv ; agg = pull (+b1, relu) ----  (pairs dead from here)
    k_gemm<128><<<(n + 127) / 128, 256, 0, stream>>>(x, W1, dinv, bufH, n);
    k_pull<<<(n + 3) / 4, 256, 0, stream>>>(bufH, dinv, row_ptr, counts, col, b1, bufA, n);

    // ---- layer 2: hs = (bufA @ W2) * dinv ; agg = pull (+b2, relu) ----
    k_gemm<64><<<(n + 127) / 128, 256, 0, stream>>>(bufA, W2, dinv, bufH, n);
    k_pull<<<(n + 3) / 4, 256, 0, stream>>>(bufH, dinv, row_ptr, counts, col, b2, bufA, n);

    // ---- decoder ----
    k_decode<<<(n + 3) / 4, 256, 0, stream>>>(bufA, Wd, bd, out, n);
}

// Round 7
// 237.610 us; speedup vs baseline: 5.8385x; 1.1300x over previous
//
#include <hip/hip_runtime.h>

#define NF 64      // hidden width (both layers)
#define NBLK 128   // chunks for the two-pass bucket sort
#define MAXNB 2048 // max buckets supported by LDS histograms (n <= 131072)

// =================== scan utilities ===================

__device__ inline int wave_incl_scan(int x, int lane) {
#pragma unroll
    for (int o = 1; o < 64; o <<= 1) { int y = __shfl_up(x, o, 64); if (lane >= o) x += y; }
    return x;
}

// 1024 elements per block (256 threads x 4); in-place safe
__global__ __launch_bounds__(256) void k_scan_a(const int* __restrict__ in, int* __restrict__ out,
                                                int* __restrict__ bsums, int n) {
    int t = threadIdx.x, lane = t & 63, wv = t >> 6;
    int base = blockIdx.x * 1024 + t * 4;
    int v[4]; int s = 0;
#pragma unroll
    for (int k = 0; k < 4; ++k) { int i = base + k; int x = (i < n) ? in[i] : 0; v[k] = s; s += x; }
    int incl = wave_incl_scan(s, lane);
    __shared__ int ws[4];
    if (lane == 63) ws[wv] = incl;
    __syncthreads();
    int wofs = 0;
#pragma unroll
    for (int w = 0; w < 4; ++w) if (w < wv) wofs += ws[w];
    int texcl = wofs + incl - s;
#pragma unroll
    for (int k = 0; k < 4; ++k) { int i = base + k; if (i < n) out[i] = texcl + v[k]; }
    if (t == 255) bsums[blockIdx.x] = wofs + incl;
}

// single-block exclusive scan over up to 2048 entries; in-place safe
__global__ __launch_bounds__(256) void k_scan_small(const int* __restrict__ cnt, int* __restrict__ ptr, int NB) {
    int t = threadIdx.x, lane = t & 63, wv = t >> 6;
    int base = t * 8;
    int local[8]; int s = 0;
#pragma unroll
    for (int k = 0; k < 8; ++k) { int i = base + k; int x = (i < NB) ? cnt[i] : 0; local[k] = s; s += x; }
    int incl = wave_incl_scan(s, lane);
    __shared__ int ws[4];
    if (lane == 63) ws[wv] = incl;
    __syncthreads();
    int wofs = 0;
#pragma unroll
    for (int w = 0; w < 4; ++w) if (w < wv) wofs += ws[w];
    int texcl = wofs + incl - s;
#pragma unroll
    for (int k = 0; k < 8; ++k) { int i = base + k; if (i < NB) ptr[i] = texcl + local[k]; }
}

// add block sums; also emit bucket pointers (bptr[b] = scanned hmat[b*NBLK], bptr[NB] = E)
__global__ __launch_bounds__(256) void k_scan_addb(int* __restrict__ data, const int* __restrict__ bsums,
                                                   int* __restrict__ bptr, int ntot, int E) {
    int i = blockIdx.x * 256 + threadIdx.x;
    if (i < ntot) {
        int v = data[i] + bsums[i >> 10];
        data[i] = v;
        if ((i & (NBLK - 1)) == 0) bptr[i / NBLK] = v;
    }
    if (i == 0) bptr[ntot / NBLK] = E;
}

// =================== contention-free bucket sort (bucket = dst >> 6) ===================

__global__ __launch_bounds__(256) void k_histA(const int* __restrict__ dst, int* __restrict__ hmat,
                                               int E, int NB, int chunk) {
    __shared__ int h[MAXNB];
    int blk = blockIdx.x;
    for (int i = threadIdx.x; i < NB; i += 256) h[i] = 0;
    __syncthreads();
    int beg = blk * chunk, end = beg + chunk; if (end > E) end = E;
    for (int e = beg + threadIdx.x; e < end; e += 256) atomicAdd(&h[dst[e] >> 6], 1);
    __syncthreads();
    for (int i = threadIdx.x; i < NB; i += 256) hmat[i * NBLK + blk] = h[i];
}

__global__ __launch_bounds__(256) void k_placeB(const int* __restrict__ src, const int* __restrict__ dst,
                                                const int* __restrict__ hmat, int* __restrict__ pairs,
                                                int E, int NB, int chunk) {
    __shared__ int cur[MAXNB];
    int blk = blockIdx.x;
    for (int i = threadIdx.x; i < NB; i += 256) cur[i] = hmat[i * NBLK + blk];
    __syncthreads();
    int beg = blk * chunk, end = beg + chunk; if (end > E) end = E;
    for (int e = beg + threadIdx.x; e < end; e += 256) {
        int s = src[e], d = dst[e];
        int off = atomicAdd(&cur[d >> 6], 1);
        pairs[off] = (s << 6) | (d & 63);
    }
}

// =================== fused node-level CSR: hist + 64-scan + row_ptr/cnt/dinv + place ===================
__global__ __launch_bounds__(256) void k_csr(const int* __restrict__ bptr, const int* __restrict__ pairs,
                                             int* __restrict__ row_ptr, int* __restrict__ cnt,
                                             float* __restrict__ dinv, int* __restrict__ col, int n) {
    __shared__ int h[64];
    __shared__ int cur[64];
    int b = blockIdx.x, t = threadIdx.x;
    if (t < 64) h[t] = 0;
    __syncthreads();
    int beg = bptr[b], end = bptr[b + 1];
    for (int j = beg + t; j < end; j += 256) atomicAdd(&h[pairs[j] & 63], 1);
    __syncthreads();
    if (t < 64) {   // wave 0: 64-wide exclusive scan of counts
        int c = h[t];
        int ex = wave_incl_scan(c, t) - c;
        int node = (b << 6) + t;
        if (node < n) {
            row_ptr[node] = beg + ex;
            cnt[node] = c;
            dinv[node] = rsqrtf(1.0f + (float)c);
        }
        cur[t] = beg + ex;
    }
    __syncthreads();
    for (int j = beg + t; j < end; j += 256) {
        int pk = pairs[j];
        int p = atomicAdd(&cur[pk & 63], 1);
        col[p] = pk >> 6;
    }
}

// =================== register-blocked GEMM ===================
// hs[n][64] = (X @ W) * dinv[row].  Block: 128 rows x 64 cols. Thread: 8 rows x 4 cols.
template<int K>
__global__ __launch_bounds__(256, 2) void k_gemm(
    const float* __restrict__ X, const float* __restrict__ W,
    const float* __restrict__ dinv, float* __restrict__ out, int n)
{
    __shared__ float Ws[K * NF];
    int t = threadIdx.x;
    for (int i = t; i < K * NF / 4; i += 256) ((float4*)Ws)[i] = ((const float4*)W)[i];
    __syncthreads();

    int c0 = (t & 15) * 4;
    int row0 = blockIdx.x * 128 + (t >> 4) * 8;

    const float* Xr[8];
#pragma unroll
    for (int r = 0; r < 8; ++r) {
        int row = row0 + r; if (row >= n) row = n - 1;   // clamp: dup loads, stores guarded
        Xr[r] = X + (size_t)row * K;
    }

    float4 acc[8];
#pragma unroll
    for (int r = 0; r < 8; ++r) acc[r] = make_float4(0.f, 0.f, 0.f, 0.f);

#pragma unroll 2
    for (int k0 = 0; k0 < K; k0 += 4) {
        float4 xv[8];
#pragma unroll
        for (int r = 0; r < 8; ++r) xv[r] = *(const float4*)(Xr[r] + k0);
        float4 w0 = *(const float4*)(&Ws[(k0 + 0) * NF + c0]);
        float4 w1 = *(const float4*)(&Ws[(k0 + 1) * NF + c0]);
        float4 w2 = *(const float4*)(&Ws[(k0 + 2) * NF + c0]);
        float4 w3 = *(const float4*)(&Ws[(k0 + 3) * NF + c0]);
#pragma unroll
        for (int r = 0; r < 8; ++r) {
            acc[r].x = fmaf(xv[r].x, w0.x, acc[r].x); acc[r].y = fmaf(xv[r].x, w0.y, acc[r].y);
            acc[r].z = fmaf(xv[r].x, w0.z, acc[r].z); acc[r].w = fmaf(xv[r].x, w0.w, acc[r].w);
            acc[r].x = fmaf(xv[r].y, w1.x, acc[r].x); acc[r].y = fmaf(xv[r].y, w1.y, acc[r].y);
            acc[r].z = fmaf(xv[r].y, w1.z, acc[r].z); acc[r].w = fmaf(xv[r].y, w1.w, acc[r].w);
            acc[r].x = fmaf(xv[r].z, w2.x, acc[r].x); acc[r].y = fmaf(xv[r].z, w2.y, acc[r].y);
            acc[r].z = fmaf(xv[r].z, w2.z, acc[r].z); acc[r].w = fmaf(xv[r].z, w2.w, acc[r].w);
            acc[r].x = fmaf(xv[r].w, w3.x, acc[r].x); acc[r].y = fmaf(xv[r].w, w3.y, acc[r].y);
            acc[r].z = fmaf(xv[r].w, w3.z, acc[r].z); acc[r].w = fmaf(xv[r].w, w3.w, acc[r].w);
        }
    }

#pragma unroll
    for (int r = 0; r < 8; ++r) {
        int row = row0 + r;
        if (row < n) {
            float di = dinv[row];
            *(float4*)(out + (size_t)row * NF + c0) =
                make_float4(acc[r].x * di, acc[r].y * di, acc[r].z * di, acc[r].w * di);
        }
    }
}

// =================== pull aggregation: one 16-lane group per dst node ===================
// r = relu( dinv[d] * (hs[d] + sum_{s in N(d)} hs[s]) + bias )
// DECODE=0: write r row;  DECODE=1: write out[d] = r . Wd + bd
template<bool DECODE>
__global__ __launch_bounds__(256) void k_pull(
    const float* __restrict__ hs, const float* __restrict__ dinv,
    const int* __restrict__ row_ptr, const int* __restrict__ cnt,
    const int* __restrict__ col, const float* __restrict__ bias,
    const float* __restrict__ Wd, const float* __restrict__ bd,
    float* __restrict__ outv, int n)
{
    int d = blockIdx.x * 16 + (threadIdx.x >> 4);
    if (d >= n) return;
    int lt = threadIdx.x & 15;            // lane in group
    int fo = lt << 2;                     // feature offset
    int grpbase = threadIdx.x & 48;       // group base lane within wave
    int beg = row_ptr[d], deg = cnt[d];

    float4 acc = *(const float4*)(hs + (size_t)d * NF + fo);   // self-loop

    for (int jb = 0; jb < deg; jb += 16) {
        int m = deg - jb; if (m > 16) m = 16;
        int idx = (lt < m) ? col[beg + jb + lt] : 0;
        for (int k = 0; k < m; k += 8) {
            float4 v[8];
#pragma unroll
            for (int u = 0; u < 8; ++u) {
                int kk = k + u; if (kk >= m) kk = m - 1;      // clamp: dup loads hit L1
                int s = __shfl(idx, grpbase + kk, 64);
                v[u] = *(const float4*)(hs + (size_t)s * NF + fo);
            }
#pragma unroll
            for (int u = 0; u < 8; ++u)
                if (k + u < m) { acc.x += v[u].x; acc.y += v[u].y; acc.z += v[u].z; acc.w += v[u].w; }
        }
    }

    float di = dinv[d];
    float4 bv = *(const float4*)(bias + fo);
    float rx = fmaxf(fmaf(acc.x, di, bv.x), 0.0f);
    float ry = fmaxf(fmaf(acc.y, di, bv.y), 0.0f);
    float rz = fmaxf(fmaf(acc.z, di, bv.z), 0.0f);
    float rw = fmaxf(fmaf(acc.w, di, bv.w), 0.0f);

    if (DECODE) {
        float4 wv = *(const float4*)(Wd + fo);
        float vsum = rx * wv.x + ry * wv.y + rz * wv.z + rw * wv.w;
#pragma unroll
        for (int o = 1; o < 16; o <<= 1) vsum += __shfl_xor(vsum, o, 64);
        if (lt == 0) outv[d] = vsum + bd[0];
    } else {
        *(float4*)(outv + (size_t)d * NF + fo) = make_float4(rx, ry, rz, rw);
    }
}

extern "C" void kernel_launch(void* const* d_in, const int* in_sizes, int n_in,
                              void* d_out, int out_size, void* d_ws, size_t ws_size,
                              hipStream_t stream) {
    const float* x  = (const float*)d_in[0];
    const int*   ei = (const int*)d_in[1];
    const float* W1 = (const float*)d_in[2];
    const float* b1 = (const float*)d_in[3];
    const float* W2 = (const float*)d_in[4];
    const float* b2 = (const float*)d_in[5];
    const float* Wd = (const float*)d_in[6];
    const float* bd = (const float*)d_in[7];
    float* out = (float*)d_out;

    int n = in_sizes[0] / 128;
    int E = in_sizes[1] / 2;
    const int* src = ei;
    const int* dst = ei + E;

    int NB = (n + 63) >> 6;                 // dst buckets of 64 nodes
    int chunk = (E + NBLK - 1) / NBLK;
    int ntot = NB * NBLK;                   // hist matrix size
    int nsb = (ntot + 1023) / 1024;         // scan blocks over hmat

    // workspace layout (4-byte elems) — pairs aliases bufH (build finishes before gemm1)
    float* dinv    = (float*)d_ws;                    // n
    float* bufH    = dinv + n;                        // 64n
    float* bufA    = bufH + (size_t)n * NF;           // 64n
    int*   counts  = (int*)(bufA + (size_t)n * NF);   // n
    int*   row_ptr = counts + n;                      // n
    int*   col     = row_ptr + n;                     // E
    int*   hmat    = col + E;                         // NB*NBLK
    int*   bptr    = hmat + ntot;                     // NB+1
    int*   bsums   = bptr + NB + 1;                   // <=1024
    int*   pairs   = (int*)bufH;                      // E (build lifetime only)

    // ---- bucket sort by dst (contention-free) ----
    k_histA<<<NBLK, 256, 0, stream>>>(dst, hmat, E, NB, chunk);
    k_scan_a<<<nsb, 256, 0, stream>>>(hmat, hmat, bsums, ntot);
    k_scan_small<<<1, 256, 0, stream>>>(bsums, bsums, nsb);
    k_scan_addb<<<(ntot + 255) / 256, 256, 0, stream>>>(hmat, bsums, bptr, ntot, E);
    k_placeB<<<NBLK, 256, 0, stream>>>(src, dst, hmat, pairs, E, NB, chunk);

    // ---- fused node-level CSR + dinv ----
    k_csr<<<NB, 256, 0, stream>>>(bptr, pairs, row_ptr, counts, dinv, col, n);

    // ---- layer 1: hs = (x @ W1) * dinv ; pull (+b1, relu) ----  (pairs dead from here)
    k_gemm<128><<<(n + 127) / 128, 256, 0, stream>>>(x, W1, dinv, bufH, n);
    k_pull<false><<<(n + 15) / 16, 256, 0, stream>>>(bufH, dinv, row_ptr, counts, col, b1,
                                                     Wd, bd, bufA, n);

    // ---- layer 2: hs = (bufA @ W2) * dinv ; pull (+b2, relu) + fused decode ----
    k_gemm<64><<<(n + 127) / 128, 256, 0, stream>>>(bufA, W2, dinv, bufH, n);
    k_pull<true><<<(n + 15) / 16, 256, 0, stream>>>(bufH, dinv, row_ptr, counts, col, b2,
                                                    Wd, bd, out, n);
}

// Round 8
// 191.618 us; speedup vs baseline: 7.2398x; 1.2400x over previous
//
#include <hip/hip_runtime.h>

#define NF 64      // hidden width (both layers)
#define NBLK 128   // chunks for the two-pass bucket sort
#define MAXNB 2048 // max buckets supported by LDS histograms (n <= 131072)

typedef unsigned short ushort_t;

__device__ inline ushort_t f2bf(float f) {               // RNE f32 -> bf16
    unsigned u = __float_as_uint(f);
    return (ushort_t)((u + 0x7fffu + ((u >> 16) & 1u)) >> 16);
}
__device__ inline float bfhi(unsigned x) { return __uint_as_float(x & 0xffff0000u); }
__device__ inline float bflo(unsigned x) { return __uint_as_float(x << 16); }

// =================== scan utilities ===================

__device__ inline int wave_incl_scan(int x, int lane) {
#pragma unroll
    for (int o = 1; o < 64; o <<= 1) { int y = __shfl_up(x, o, 64); if (lane >= o) x += y; }
    return x;
}

// 1024 elements per block (256 threads x 4); in-place safe
__global__ __launch_bounds__(256) void k_scan_a(const int* __restrict__ in, int* __restrict__ out,
                                                int* __restrict__ bsums, int n) {
    int t = threadIdx.x, lane = t & 63, wv = t >> 6;
    int base = blockIdx.x * 1024 + t * 4;
    int v[4]; int s = 0;
#pragma unroll
    for (int k = 0; k < 4; ++k) { int i = base + k; int x = (i < n) ? in[i] : 0; v[k] = s; s += x; }
    int incl = wave_incl_scan(s, lane);
    __shared__ int ws[4];
    if (lane == 63) ws[wv] = incl;
    __syncthreads();
    int wofs = 0;
#pragma unroll
    for (int w = 0; w < 4; ++w) if (w < wv) wofs += ws[w];
    int texcl = wofs + incl - s;
#pragma unroll
    for (int k = 0; k < 4; ++k) { int i = base + k; if (i < n) out[i] = texcl + v[k]; }
    if (t == 255) bsums[blockIdx.x] = wofs + incl;
}

// single-block exclusive scan over up to 2048 entries; in-place safe
__global__ __launch_bounds__(256) void k_scan_small(const int* __restrict__ cnt, int* __restrict__ ptr, int NB) {
    int t = threadIdx.x, lane = t & 63, wv = t >> 6;
    int base = t * 8;
    int local[8]; int s = 0;
#pragma unroll
    for (int k = 0; k < 8; ++k) { int i = base + k; int x = (i < NB) ? cnt[i] : 0; local[k] = s; s += x; }
    int incl = wave_incl_scan(s, lane);
    __shared__ int ws[4];
    if (lane == 63) ws[wv] = incl;
    __syncthreads();
    int wofs = 0;
#pragma unroll
    for (int w = 0; w < 4; ++w) if (w < wv) wofs += ws[w];
    int texcl = wofs + incl - s;
#pragma unroll
    for (int k = 0; k < 8; ++k) { int i = base + k; if (i < NB) ptr[i] = texcl + local[k]; }
}

// add block sums; also emit bucket pointers (bptr[b] = scanned hmat[b*NBLK], bptr[NB] = E)
__global__ __launch_bounds__(256) void k_scan_addb(int* __restrict__ data, const int* __restrict__ bsums,
                                                   int* __restrict__ bptr, int ntot, int E) {
    int i = blockIdx.x * 256 + threadIdx.x;
    if (i < ntot) {
        int v = data[i] + bsums[i >> 10];
        data[i] = v;
        if ((i & (NBLK - 1)) == 0) bptr[i / NBLK] = v;
    }
    if (i == 0) bptr[ntot / NBLK] = E;
}

// =================== contention-free bucket sort (bucket = dst >> 6) ===================

__global__ __launch_bounds__(256) void k_histA(const int* __restrict__ dst, int* __restrict__ hmat,
                                               int E, int NB, int chunk) {
    __shared__ int h[MAXNB];
    int blk = blockIdx.x;
    for (int i = threadIdx.x; i < NB; i += 256) h[i] = 0;
    __syncthreads();
    int beg = blk * chunk, end = beg + chunk; if (end > E) end = E;
    for (int e = beg + threadIdx.x; e < end; e += 256) atomicAdd(&h[dst[e] >> 6], 1);
    __syncthreads();
    for (int i = threadIdx.x; i < NB; i += 256) hmat[i * NBLK + blk] = h[i];
}

__global__ __launch_bounds__(256) void k_placeB(const int* __restrict__ src, const int* __restrict__ dst,
                                                const int* __restrict__ hmat, int* __restrict__ pairs,
                                                int E, int NB, int chunk) {
    __shared__ int cur[MAXNB];
    int blk = blockIdx.x;
    for (int i = threadIdx.x; i < NB; i += 256) cur[i] = hmat[i * NBLK + blk];
    __syncthreads();
    int beg = blk * chunk, end = beg + chunk; if (end > E) end = E;
    for (int e = beg + threadIdx.x; e < end; e += 256) {
        int s = src[e], d = dst[e];
        int off = atomicAdd(&cur[d >> 6], 1);
        pairs[off] = (s << 6) | (d & 63);
    }
}

// =================== fused node-level CSR: hist + 64-scan + row_ptr/cnt/dinv + place ===================
__global__ __launch_bounds__(256) void k_csr(const int* __restrict__ bptr, const int* __restrict__ pairs,
                                             int* __restrict__ row_ptr, int* __restrict__ cnt,
                                             float* __restrict__ dinv, int* __restrict__ col, int n) {
    __shared__ int h[64];
    __shared__ int cur[64];
    int b = blockIdx.x, t = threadIdx.x;
    if (t < 64) h[t] = 0;
    __syncthreads();
    int beg = bptr[b], end = bptr[b + 1];
    for (int j = beg + t; j < end; j += 256) atomicAdd(&h[pairs[j] & 63], 1);
    __syncthreads();
    if (t < 64) {
        int c = h[t];
        int ex = wave_incl_scan(c, t) - c;
        int node = (b << 6) + t;
        if (node < n) {
            row_ptr[node] = beg + ex;
            cnt[node] = c;
            dinv[node] = rsqrtf(1.0f + (float)c);
        }
        cur[t] = beg + ex;
    }
    __syncthreads();
    for (int j = beg + t; j < end; j += 256) {
        int pk = pairs[j];
        int p = atomicAdd(&cur[pk & 63], 1);
        col[p] = pk >> 6;
    }
}

// =================== register-blocked GEMM ===================
// hs[n][64](bf16) = (X @ W) * dinv[row].  Block: 128 rows x 64 cols. Thread: 8 rows x 4 cols.
template<int K>
__global__ __launch_bounds__(256, 2) void k_gemm(
    const float* __restrict__ X, const float* __restrict__ W,
    const float* __restrict__ dinv, ushort_t* __restrict__ out, int n)
{
    __shared__ float Ws[K * NF];
    int t = threadIdx.x;
    for (int i = t; i < K * NF / 4; i += 256) ((float4*)Ws)[i] = ((const float4*)W)[i];
    __syncthreads();

    int c0 = (t & 15) * 4;
    int row0 = blockIdx.x * 128 + (t >> 4) * 8;

    const float* Xr[8];
#pragma unroll
    for (int r = 0; r < 8; ++r) {
        int row = row0 + r; if (row >= n) row = n - 1;   // clamp: dup loads, stores guarded
        Xr[r] = X + (size_t)row * K;
    }

    float4 acc[8];
#pragma unroll
    for (int r = 0; r < 8; ++r) acc[r] = make_float4(0.f, 0.f, 0.f, 0.f);

#pragma unroll 2
    for (int k0 = 0; k0 < K; k0 += 4) {
        float4 xv[8];
#pragma unroll
        for (int r = 0; r < 8; ++r) xv[r] = *(const float4*)(Xr[r] + k0);
        float4 w0 = *(const float4*)(&Ws[(k0 + 0) * NF + c0]);
        float4 w1 = *(const float4*)(&Ws[(k0 + 1) * NF + c0]);
        float4 w2 = *(const float4*)(&Ws[(k0 + 2) * NF + c0]);
        float4 w3 = *(const float4*)(&Ws[(k0 + 3) * NF + c0]);
#pragma unroll
        for (int r = 0; r < 8; ++r) {
            acc[r].x = fmaf(xv[r].x, w0.x, acc[r].x); acc[r].y = fmaf(xv[r].x, w0.y, acc[r].y);
            acc[r].z = fmaf(xv[r].x, w0.z, acc[r].z); acc[r].w = fmaf(xv[r].x, w0.w, acc[r].w);
            acc[r].x = fmaf(xv[r].y, w1.x, acc[r].x); acc[r].y = fmaf(xv[r].y, w1.y, acc[r].y);
            acc[r].z = fmaf(xv[r].y, w1.z, acc[r].z); acc[r].w = fmaf(xv[r].y, w1.w, acc[r].w);
            acc[r].x = fmaf(xv[r].z, w2.x, acc[r].x); acc[r].y = fmaf(xv[r].z, w2.y, acc[r].y);
            acc[r].z = fmaf(xv[r].z, w2.z, acc[r].z); acc[r].w = fmaf(xv[r].z, w2.w, acc[r].w);
            acc[r].x = fmaf(xv[r].w, w3.x, acc[r].x); acc[r].y = fmaf(xv[r].w, w3.y, acc[r].y);
            acc[r].z = fmaf(xv[r].w, w3.z, acc[r].z); acc[r].w = fmaf(xv[r].w, w3.w, acc[r].w);
        }
    }

#pragma unroll
    for (int r = 0; r < 8; ++r) {
        int row = row0 + r;
        if (row < n) {
            float di = dinv[row];
            ushort4 o;
            o.x = f2bf(acc[r].x * di); o.y = f2bf(acc[r].y * di);
            o.z = f2bf(acc[r].z * di); o.w = f2bf(acc[r].w * di);
            *(ushort4*)(out + (size_t)row * NF + c0) = o;
        }
    }
}

// =================== pull aggregation: one 16-lane group per dst node, bf16 rows ===================
// r = relu( dinv[d] * (hs[d] + sum_{s in N(d)} hs[s]) + bias )
// DECODE=0: write r row (f32);  DECODE=1: write out[d] = r . Wd + bd
template<bool DECODE>
__global__ __launch_bounds__(256) void k_pull(
    const ushort_t* __restrict__ hs, const float* __restrict__ dinv,
    const int* __restrict__ row_ptr, const int* __restrict__ cnt,
    const int* __restrict__ col, const float* __restrict__ bias,
    const float* __restrict__ Wd, const float* __restrict__ bd,
    float* __restrict__ outv, int n)
{
    int d = blockIdx.x * 16 + (threadIdx.x >> 4);
    if (d >= n) return;
    int lt = threadIdx.x & 15;            // lane in group
    int fo = lt << 2;                     // feature offset (4 features/lane)
    int grpbase = threadIdx.x & 48;       // group base lane within wave
    int beg = row_ptr[d], deg = cnt[d];

    // self-loop (bf16 row, 8B/lane)
    uint2 sv = *((const uint2*)(hs + (size_t)d * NF) + lt);
    float4 acc = make_float4(bflo(sv.x), bfhi(sv.x), bflo(sv.y), bfhi(sv.y));

    for (int jb = 0; jb < deg; jb += 16) {
        int m = deg - jb; if (m > 16) m = 16;
        int idx = (lt < m) ? col[beg + jb + lt] : 0;
        uint2 v[16];
#pragma unroll
        for (int u = 0; u < 16; ++u) {
            int kk = (u < m) ? u : (m - 1);                  // clamp: dup loads hit L1
            int s = __shfl(idx, grpbase + kk, 64);
            v[u] = *((const uint2*)(hs + (size_t)s * NF) + lt);
        }
#pragma unroll
        for (int u = 0; u < 16; ++u) {
            if (u < m) {
                acc.x += bflo(v[u].x); acc.y += bfhi(v[u].x);
                acc.z += bflo(v[u].y); acc.w += bfhi(v[u].y);
            }
        }
    }

    float di = dinv[d];
    float4 bv = *(const float4*)(bias + fo);
    float rx = fmaxf(fmaf(acc.x, di, bv.x), 0.0f);
    float ry = fmaxf(fmaf(acc.y, di, bv.y), 0.0f);
    float rz = fmaxf(fmaf(acc.z, di, bv.z), 0.0f);
    float rw = fmaxf(fmaf(acc.w, di, bv.w), 0.0f);

    if (DECODE) {
        float4 wv = *(const float4*)(Wd + fo);
        float vsum = rx * wv.x + ry * wv.y + rz * wv.z + rw * wv.w;
#pragma unroll
        for (int o = 1; o < 16; o <<= 1) vsum += __shfl_xor(vsum, o, 64);
        if (lt == 0) outv[d] = vsum + bd[0];
    } else {
        *(float4*)(outv + (size_t)d * NF + fo) = make_float4(rx, ry, rz, rw);
    }
}

extern "C" void kernel_launch(void* const* d_in, const int* in_sizes, int n_in,
                              void* d_out, int out_size, void* d_ws, size_t ws_size,
                              hipStream_t stream) {
    const float* x  = (const float*)d_in[0];
    const int*   ei = (const int*)d_in[1];
    const float* W1 = (const float*)d_in[2];
    const float* b1 = (const float*)d_in[3];
    const float* W2 = (const float*)d_in[4];
    const float* b2 = (const float*)d_in[5];
    const float* Wd = (const float*)d_in[6];
    const float* bd = (const float*)d_in[7];
    float* out = (float*)d_out;

    int n = in_sizes[0] / 128;
    int E = in_sizes[1] / 2;
    const int* src = ei;
    const int* dst = ei + E;

    int NB = (n + 63) >> 6;                 // dst buckets of 64 nodes
    int chunk = (E + NBLK - 1) / NBLK;
    int ntot = NB * NBLK;                   // hist matrix size
    int nsb = (ntot + 1023) / 1024;         // scan blocks over hmat

    // workspace layout (4-byte elems) — pairs aliases bufH region (build ends before gemm1)
    float* dinv    = (float*)d_ws;                    // n
    float* bufH    = dinv + n;                        // 64n f32 region; used as bf16 (32n f32 worth)
    float* bufA    = bufH + (size_t)n * NF;           // 64n f32
    int*   counts  = (int*)(bufA + (size_t)n * NF);   // n
    int*   row_ptr = counts + n;                      // n
    int*   col     = row_ptr + n;                     // E
    int*   hmat    = col + E;                         // NB*NBLK
    int*   bptr    = hmat + ntot;                     // NB+1
    int*   bsums   = bptr + NB + 1;                   // <=1024
    int*   pairs   = (int*)bufH;                      // E (build lifetime only)
    ushort_t* hsb  = (ushort_t*)bufH;                 // 64n bf16 (post-build lifetime)

    // ---- bucket sort by dst (contention-free) ----
    k_histA<<<NBLK, 256, 0, stream>>>(dst, hmat, E, NB, chunk);
    k_scan_a<<<nsb, 256, 0, stream>>>(hmat, hmat, bsums, ntot);
    k_scan_small<<<1, 256, 0, stream>>>(bsums, bsums, nsb);
    k_scan_addb<<<(ntot + 255) / 256, 256, 0, stream>>>(hmat, bsums, bptr, ntot, E);
    k_placeB<<<NBLK, 256, 0, stream>>>(src, dst, hmat, pairs, E, NB, chunk);

    // ---- fused node-level CSR + dinv ----
    k_csr<<<NB, 256, 0, stream>>>(bptr, pairs, row_ptr, counts, dinv, col, n);

    // ---- layer 1: hs = bf16((x @ W1) * dinv) ; pull (+b1, relu) ----  (pairs dead from here)
    k_gemm<128><<<(n + 127) / 128, 256, 0, stream>>>(x, W1, dinv, hsb, n);
    k_pull<false><<<(n + 15) / 16, 256, 0, stream>>>(hsb, dinv, row_ptr, counts, col, b1,
                                                     Wd, bd, bufA, n);

    // ---- layer 2: hs = bf16((bufA @ W2) * dinv) ; pull (+b2, relu) + fused decode ----
    k_gemm<64><<<(n + 127) / 128, 256, 0, stream>>>(bufA, W2, dinv, hsb, n);
    k_pull<true><<<(n + 15) / 16, 256, 0, stream>>>(hsb, dinv, row_ptr, counts, col, b2,
                                                    Wd, bd, out, n);
}

// Round 9
// 180.009 us; speedup vs baseline: 7.7067x; 1.0645x over previous
//
#include <hip/hip_runtime.h>

#define NF 64      // hidden width (both layers)
#define NBLK 128   // chunks for the two-pass bucket sort
#define MAXNB 2048 // max buckets supported by LDS histograms (n <= 131072)

typedef unsigned short ushort_t;

__device__ inline ushort_t f2bf(float f) {               // RNE f32 -> bf16
    unsigned u = __float_as_uint(f);
    return (ushort_t)((u + 0x7fffu + ((u >> 16) & 1u)) >> 16);
}
__device__ inline float bfhi(unsigned x) { return __uint_as_float(x & 0xffff0000u); }
__device__ inline float bflo(unsigned x) { return __uint_as_float(x << 16); }

// =================== scan utilities ===================

__device__ inline int wave_incl_scan(int x, int lane) {
#pragma unroll
    for (int o = 1; o < 64; o <<= 1) { int y = __shfl_up(x, o, 64); if (lane >= o) x += y; }
    return x;
}

// 1024 elements per block (256 threads x 4); in-place safe
__global__ __launch_bounds__(256) void k_scan_a(const int* __restrict__ in, int* __restrict__ out,
                                                int* __restrict__ bsums, int n) {
    int t = threadIdx.x, lane = t & 63, wv = t >> 6;
    int base = blockIdx.x * 1024 + t * 4;
    int v[4]; int s = 0;
#pragma unroll
    for (int k = 0; k < 4; ++k) { int i = base + k; int x = (i < n) ? in[i] : 0; v[k] = s; s += x; }
    int incl = wave_incl_scan(s, lane);
    __shared__ int ws[4];
    if (lane == 63) ws[wv] = incl;
    __syncthreads();
    int wofs = 0;
#pragma unroll
    for (int w = 0; w < 4; ++w) if (w < wv) wofs += ws[w];
    int texcl = wofs + incl - s;
#pragma unroll
    for (int k = 0; k < 4; ++k) { int i = base + k; if (i < n) out[i] = texcl + v[k]; }
    if (t == 255) bsums[blockIdx.x] = wofs + incl;
}

// single-block exclusive scan over up to 2048 entries; in-place safe
__global__ __launch_bounds__(256) void k_scan_small(const int* __restrict__ cnt, int* __restrict__ ptr, int NB) {
    int t = threadIdx.x, lane = t & 63, wv = t >> 6;
    int base = t * 8;
    int local[8]; int s = 0;
#pragma unroll
    for (int k = 0; k < 8; ++k) { int i = base + k; int x = (i < NB) ? cnt[i] : 0; local[k] = s; s += x; }
    int incl = wave_incl_scan(s, lane);
    __shared__ int ws[4];
    if (lane == 63) ws[wv] = incl;
    __syncthreads();
    int wofs = 0;
#pragma unroll
    for (int w = 0; w < 4; ++w) if (w < wv) wofs += ws[w];
    int texcl = wofs + incl - s;
#pragma unroll
    for (int k = 0; k < 8; ++k) { int i = base + k; if (i < NB) ptr[i] = texcl + local[k]; }
}

// add block sums; also emit bucket pointers (bptr[b] = scanned hmat[b*NBLK], bptr[NB] = E)
__global__ __launch_bounds__(256) void k_scan_addb(int* __restrict__ data, const int* __restrict__ bsums,
                                                   int* __restrict__ bptr, int ntot, int E) {
    int i = blockIdx.x * 256 + threadIdx.x;
    if (i < ntot) {
        int v = data[i] + bsums[i >> 10];
        data[i] = v;
        if ((i & (NBLK - 1)) == 0) bptr[i / NBLK] = v;
    }
    if (i == 0) bptr[ntot / NBLK] = E;
}

// =================== contention-free bucket sort (bucket = dst >> 6) ===================

__global__ __launch_bounds__(256) void k_histA(const int* __restrict__ dst, int* __restrict__ hmat,
                                               int E, int NB, int chunk) {
    __shared__ int h[MAXNB];
    int blk = blockIdx.x;
    for (int i = threadIdx.x; i < NB; i += 256) h[i] = 0;
    __syncthreads();
    int beg = blk * chunk, end = beg + chunk; if (end > E) end = E;
    for (int e = beg + threadIdx.x; e < end; e += 256) atomicAdd(&h[dst[e] >> 6], 1);
    __syncthreads();
    for (int i = threadIdx.x; i < NB; i += 256) hmat[i * NBLK + blk] = h[i];
}

__global__ __launch_bounds__(256) void k_placeB(const int* __restrict__ src, const int* __restrict__ dst,
                                                const int* __restrict__ hmat, int* __restrict__ pairs,
                                                int E, int NB, int chunk) {
    __shared__ int cur[MAXNB];
    int blk = blockIdx.x;
    for (int i = threadIdx.x; i < NB; i += 256) cur[i] = hmat[i * NBLK + blk];
    __syncthreads();
    int beg = blk * chunk, end = beg + chunk; if (end > E) end = E;
    for (int e = beg + threadIdx.x; e < end; e += 256) {
        int s = src[e], d = dst[e];
        int off = atomicAdd(&cur[d >> 6], 1);
        pairs[off] = (s << 6) | (d & 63);
    }
}

// =================== fused node-level CSR: hist + 64-scan + row_ptr/cnt/dinv + place ===================
__global__ __launch_bounds__(256) void k_csr(const int* __restrict__ bptr, const int* __restrict__ pairs,
                                             int* __restrict__ row_ptr, int* __restrict__ cnt,
                                             float* __restrict__ dinv, int* __restrict__ col, int n) {
    __shared__ int h[64];
    __shared__ int cur[64];
    int b = blockIdx.x, t = threadIdx.x;
    if (t < 64) h[t] = 0;
    __syncthreads();
    int beg = bptr[b], end = bptr[b + 1];
    for (int j = beg + t; j < end; j += 256) atomicAdd(&h[pairs[j] & 63], 1);
    __syncthreads();
    if (t < 64) {
        int c = h[t];
        int ex = wave_incl_scan(c, t) - c;
        int node = (b << 6) + t;
        if (node < n) {
            row_ptr[node] = beg + ex;
            cnt[node] = c;
            dinv[node] = rsqrtf(1.0f + (float)c);
        }
        cur[t] = beg + ex;
    }
    __syncthreads();
    for (int j = beg + t; j < end; j += 256) {
        int pk = pairs[j];
        int p = atomicAdd(&cur[pk & 63], 1);
        col[p] = pk >> 6;
    }
}

// =================== register-blocked GEMM (occupancy-tuned) ===================
// hs[n][64](bf16) = (X @ W) * dinv[row].  Block: 64 rows x 64 cols. Thread: 4 rows x 4 cols.
// Grid ~ n/64 = 1563 blocks (~6/CU). VGPR pinned <=64 via launch_bounds min-waves=8.
template<int K>
__global__ __launch_bounds__(256, 8) void k_gemm(
    const float* __restrict__ X, const float* __restrict__ W,
    const float* __restrict__ dinv, ushort_t* __restrict__ out, int n)
{
    __shared__ float Ws[K * NF];
    int t = threadIdx.x;
    for (int i = t; i < K * NF / 4; i += 256) ((float4*)Ws)[i] = ((const float4*)W)[i];
    __syncthreads();

    int c0 = (t & 15) * 4;                       // 16 col-groups x 4 cols
    int row0 = blockIdx.x * 64 + (t >> 4) * 4;   // 16 row-groups x 4 rows

    const float* Xr[4];
#pragma unroll
    for (int r = 0; r < 4; ++r) {
        int row = row0 + r; if (row >= n) row = n - 1;   // clamp: dup loads, stores guarded
        Xr[r] = X + (size_t)row * K;
    }

    float4 acc[4];
#pragma unroll
    for (int r = 0; r < 4; ++r) acc[r] = make_float4(0.f, 0.f, 0.f, 0.f);

#pragma unroll 2
    for (int k0 = 0; k0 < K; k0 += 4) {
        float4 xv[4];
#pragma unroll
        for (int r = 0; r < 4; ++r) xv[r] = *(const float4*)(Xr[r] + k0);
        float4 w0 = *(const float4*)(&Ws[(k0 + 0) * NF + c0]);
        float4 w1 = *(const float4*)(&Ws[(k0 + 1) * NF + c0]);
        float4 w2 = *(const float4*)(&Ws[(k0 + 2) * NF + c0]);
        float4 w3 = *(const float4*)(&Ws[(k0 + 3) * NF + c0]);
#pragma unroll
        for (int r = 0; r < 4; ++r) {
            acc[r].x = fmaf(xv[r].x, w0.x, acc[r].x); acc[r].y = fmaf(xv[r].x, w0.y, acc[r].y);
            acc[r].z = fmaf(xv[r].x, w0.z, acc[r].z); acc[r].w = fmaf(xv[r].x, w0.w, acc[r].w);
            acc[r].x = fmaf(xv[r].y, w1.x, acc[r].x); acc[r].y = fmaf(xv[r].y, w1.y, acc[r].y);
            acc[r].z = fmaf(xv[r].y, w1.z, acc[r].z); acc[r].w = fmaf(xv[r].y, w1.w, acc[r].w);
            acc[r].x = fmaf(xv[r].z, w2.x, acc[r].x); acc[r].y = fmaf(xv[r].z, w2.y, acc[r].y);
            acc[r].z = fmaf(xv[r].z, w2.z, acc[r].z); acc[r].w = fmaf(xv[r].z, w2.w, acc[r].w);
            acc[r].x = fmaf(xv[r].w, w3.x, acc[r].x); acc[r].y = fmaf(xv[r].w, w3.y, acc[r].y);
            acc[r].z = fmaf(xv[r].w, w3.z, acc[r].z); acc[r].w = fmaf(xv[r].w, w3.w, acc[r].w);
        }
    }

#pragma unroll
    for (int r = 0; r < 4; ++r) {
        int row = row0 + r;
        if (row < n) {
            float di = dinv[row];
            ushort4 o;
            o.x = f2bf(acc[r].x * di); o.y = f2bf(acc[r].y * di);
            o.z = f2bf(acc[r].z * di); o.w = f2bf(acc[r].w * di);
            *(ushort4*)(out + (size_t)row * NF + c0) = o;
        }
    }
}

// =================== pull aggregation: one 16-lane group per dst node, bf16 rows ===================
// r = relu( dinv[d] * (hs[d] + sum_{s in N(d)} hs[s]) + bias )
// DECODE=0: write r row (f32);  DECODE=1: write out[d] = r . Wd + bd
template<bool DECODE>
__global__ __launch_bounds__(256) void k_pull(
    const ushort_t* __restrict__ hs, const float* __restrict__ dinv,
    const int* __restrict__ row_ptr, const int* __restrict__ cnt,
    const int* __restrict__ col, const float* __restrict__ bias,
    const float* __restrict__ Wd, const float* __restrict__ bd,
    float* __restrict__ outv, int n)
{
    int d = blockIdx.x * 16 + (threadIdx.x >> 4);
    if (d >= n) return;
    int lt = threadIdx.x & 15;            // lane in group
    int fo = lt << 2;                     // feature offset (4 features/lane)
    int grpbase = threadIdx.x & 48;       // group base lane within wave
    int beg = row_ptr[d], deg = cnt[d];

    // self-loop (bf16 row, 8B/lane)
    uint2 sv = *((const uint2*)(hs + (size_t)d * NF) + lt);
    float4 acc = make_float4(bflo(sv.x), bfhi(sv.x), bflo(sv.y), bfhi(sv.y));

    for (int jb = 0; jb < deg; jb += 16) {
        int m = deg - jb; if (m > 16) m = 16;
        int idx = (lt < m) ? col[beg + jb + lt] : 0;
        uint2 v[16];
#pragma unroll
        for (int u = 0; u < 16; ++u) {
            int kk = (u < m) ? u : (m - 1);                  // clamp: dup loads hit L1
            int s = __shfl(idx, grpbase + kk, 64);
            v[u] = *((const uint2*)(hs + (size_t)s * NF) + lt);
        }
#pragma unroll
        for (int u = 0; u < 16; ++u) {
            if (u < m) {
                acc.x += bflo(v[u].x); acc.y += bfhi(v[u].x);
                acc.z += bflo(v[u].y); acc.w += bfhi(v[u].y);
            }
        }
    }

    float di = dinv[d];
    float4 bv = *(const float4*)(bias + fo);
    float rx = fmaxf(fmaf(acc.x, di, bv.x), 0.0f);
    float ry = fmaxf(fmaf(acc.y, di, bv.y), 0.0f);
    float rz = fmaxf(fmaf(acc.z, di, bv.z), 0.0f);
    float rw = fmaxf(fmaf(acc.w, di, bv.w), 0.0f);

    if (DECODE) {
        float4 wv = *(const float4*)(Wd + fo);
        float vsum = rx * wv.x + ry * wv.y + rz * wv.z + rw * wv.w;
#pragma unroll
        for (int o = 1; o < 16; o <<= 1) vsum += __shfl_xor(vsum, o, 64);
        if (lt == 0) outv[d] = vsum + bd[0];
    } else {
        *(float4*)(outv + (size_t)d * NF + fo) = make_float4(rx, ry, rz, rw);
    }
}

extern "C" void kernel_launch(void* const* d_in, const int* in_sizes, int n_in,
                              void* d_out, int out_size, void* d_ws, size_t ws_size,
                              hipStream_t stream) {
    const float* x  = (const float*)d_in[0];
    const int*   ei = (const int*)d_in[1];
    const float* W1 = (const float*)d_in[2];
    const float* b1 = (const float*)d_in[3];
    const float* W2 = (const float*)d_in[4];
    const float* b2 = (const float*)d_in[5];
    const float* Wd = (const float*)d_in[6];
    const float* bd = (const float*)d_in[7];
    float* out = (float*)d_out;

    int n = in_sizes[0] / 128;
    int E = in_sizes[1] / 2;
    const int* src = ei;
    const int* dst = ei + E;

    int NB = (n + 63) >> 6;                 // dst buckets of 64 nodes
    int chunk = (E + NBLK - 1) / NBLK;
    int ntot = NB * NBLK;                   // hist matrix size
    int nsb = (ntot + 1023) / 1024;         // scan blocks over hmat

    // workspace layout (4-byte elems) — pairs aliases bufH region (build ends before gemm1)
    float* dinv    = (float*)d_ws;                    // n
    float* bufH    = dinv + n;                        // 64n f32 region; used as bf16 (32n f32 worth)
    float* bufA    = bufH + (size_t)n * NF;           // 64n f32
    int*   counts  = (int*)(bufA + (size_t)n * NF);   // n
    int*   row_ptr = counts + n;                      // n
    int*   col     = row_ptr + n;                     // E
    int*   hmat    = col + E;                         // NB*NBLK
    int*   bptr    = hmat + ntot;                     // NB+1
    int*   bsums   = bptr + NB + 1;                   // <=1024
    int*   pairs   = (int*)bufH;                      // E (build lifetime only)
    ushort_t* hsb  = (ushort_t*)bufH;                 // 64n bf16 (post-build lifetime)

    // ---- bucket sort by dst (contention-free) ----
    k_histA<<<NBLK, 256, 0, stream>>>(dst, hmat, E, NB, chunk);
    k_scan_a<<<nsb, 256, 0, stream>>>(hmat, hmat, bsums, ntot);
    k_scan_small<<<1, 256, 0, stream>>>(bsums, bsums, nsb);
    k_scan_addb<<<(ntot + 255) / 256, 256, 0, stream>>>(hmat, bsums, bptr, ntot, E);
    k_placeB<<<NBLK, 256, 0, stream>>>(src, dst, hmat, pairs, E, NB, chunk);

    // ---- fused node-level CSR + dinv ----
    k_csr<<<NB, 256, 0, stream>>>(bptr, pairs, row_ptr, counts, dinv, col, n);

    // ---- layer 1: hs = bf16((x @ W1) * dinv) ; pull (+b1, relu) ----  (pairs dead from here)
    k_gemm<128><<<(n + 63) / 64, 256, 0, stream>>>(x, W1, dinv, hsb, n);
    k_pull<false><<<(n + 15) / 16, 256, 0, stream>>>(hsb, dinv, row_ptr, counts, col, b1,
                                                     Wd, bd, bufA, n);

    // ---- layer 2: hs = bf16((bufA @ W2) * dinv) ; pull (+b2, relu) + fused decode ----
    k_gemm<64><<<(n + 63) / 64, 256, 0, stream>>>(bufA, W2, dinv, hsb, n);
    k_pull<true><<<(n + 15) / 16, 256, 0, stream>>>(hsb, dinv, row_ptr, counts, col, b2,
                                                    Wd, bd, out, n);
}